// Round 11
// baseline (106.996 us; speedup 1.0000x reference)
//
#include <hip/hip_runtime.h>

// lat [2048,2048] fp32 -> 131072 rows x D=32; centroids [1024,32] fp32.
// out = [lat * clamp(lf,1e-3,1e3)] ++ [1.25 * mean_{N,D}(min_k ||z-c_k||^2)]
#define D 32
#define K 1024
#define N_ROWS 131072
#define TOTAL_ELEMS 4194304
#define LOSS_SCALE (1.25f / 4194304.0f)
#define BIAS 192.0f   // score = ||c||^2 - 2 z.c + BIAS > 0 -> uint-comparable

typedef __attribute__((ext_vector_type(8))) short short8;   // 8 bf16
typedef __attribute__((ext_vector_type(4))) float f32x4;

__device__ __forceinline__ unsigned short f2bf(float f) {
  unsigned u = __builtin_bit_cast(unsigned, f);
  unsigned r = u + 0x7FFFu + ((u >> 16) & 1u);   // RNE
  return (unsigned short)(r >> 16);
}

// ---- prep: centbf = bf16(-2c); cnormb = ||c||^2 + BIAS; zero loss slot ----
__global__ __launch_bounds__(256) void prep_kernel(
    const float* __restrict__ cent, unsigned short* __restrict__ centbf,
    float* __restrict__ cnormb, float* __restrict__ loss_out) {
  int t = blockIdx.x * 256 + threadIdx.x;   // 0..32767
  centbf[t] = f2bf(-2.0f * cent[t]);
  if (t == 0) *loss_out = 0.0f;
  if (t < K) {
    const float* c = cent + t * D;
    float s0 = 0.f, s1 = 0.f, s2 = 0.f, s3 = 0.f;
#pragma unroll
    for (int d = 0; d < D; d += 4) {
      s0 = fmaf(c[d], c[d], s0);
      s1 = fmaf(c[d + 1], c[d + 1], s1);
      s2 = fmaf(c[d + 2], c[d + 2], s2);
      s3 = fmaf(c[d + 3], c[d + 3], s3);
    }
    cnormb[t] = (s0 + s1) + (s2 + s3) + BIAS;
  }
}

// ---- vq_main: half-codebook blocks, barrier-free, 4 blocks/CU -------------
// Grid 2048 = 1024 row-groups x 2 halves. Block stages 32KB (512 cents) +
// 2KB cn; wave = 32 rows (r7-verified 2-tile body, 32 f-iters); packed
// (score|idx) winner per row written to ws. No barriers after the stage.
__global__ __launch_bounds__(256) void vq_main(
    const float* __restrict__ lat, const unsigned short* __restrict__ centbf,
    const float* __restrict__ cnormb, const float* __restrict__ lf_ptr,
    float* __restrict__ out, unsigned* __restrict__ wswin) {
  __shared__ short8 sB8[2048];   // 32 KB: 512 centroids x 32 bf16
  __shared__ float sCn[512];     // 2 KB
  const int tid = threadIdx.x;
  const int lane = tid & 63;
  const int wave = tid >> 6;
  const int quad = lane >> 4;
  const int col  = lane & 15;
  const int half = blockIdx.x & 1;
  const int rowbase = (blockIdx.x >> 1) * 128 + wave * 32;

  // Stage this half's codebook slice + cnorm slice (coalesced).
  {
    const short8* gB8 = (const short8*)centbf;   // 4096 chunks total
#pragma unroll
    for (int j = 0; j < 8; ++j)
      sB8[j * 256 + tid] = gB8[half * 2048 + j * 256 + tid];
    sCn[tid] = cnormb[half * 512 + tid];
    sCn[256 + tid] = cnormb[half * 512 + 256 + tid];
  }

  // A-frags (r7-verified) + fused scale-store (half-0 blocks only).
  float lf = fminf(fmaxf(lf_ptr[0], 0.001f), 1000.0f);
  short8 a0, a1;
  {
    const float* p0 = lat + (size_t)(rowbase + col) * D + quad * 8;
    const float* p1 = p0 + 16 * D;
    float4 u0 = ((const float4*)p0)[0], u1 = ((const float4*)p0)[1];
    float4 w0 = ((const float4*)p1)[0], w1 = ((const float4*)p1)[1];
    a0[0] = (short)f2bf(u0.x); a0[1] = (short)f2bf(u0.y);
    a0[2] = (short)f2bf(u0.z); a0[3] = (short)f2bf(u0.w);
    a0[4] = (short)f2bf(u1.x); a0[5] = (short)f2bf(u1.y);
    a0[6] = (short)f2bf(u1.z); a0[7] = (short)f2bf(u1.w);
    a1[0] = (short)f2bf(w0.x); a1[1] = (short)f2bf(w0.y);
    a1[2] = (short)f2bf(w0.z); a1[3] = (short)f2bf(w0.w);
    a1[4] = (short)f2bf(w1.x); a1[5] = (short)f2bf(w1.y);
    a1[6] = (short)f2bf(w1.z); a1[7] = (short)f2bf(w1.w);
    if (half == 0) {
      float* o0 = out + (size_t)(rowbase + col) * D + quad * 8;
      float* o1 = o0 + 16 * D;
      float4 s00 = {u0.x * lf, u0.y * lf, u0.z * lf, u0.w * lf};
      float4 s01 = {u1.x * lf, u1.y * lf, u1.z * lf, u1.w * lf};
      float4 s10 = {w0.x * lf, w0.y * lf, w0.z * lf, w0.w * lf};
      float4 s11 = {w1.x * lf, w1.y * lf, w1.z * lf, w1.w * lf};
      ((float4*)o0)[0] = s00;
      ((float4*)o0)[1] = s01;
      ((float4*)o1)[0] = s10;
      ((float4*)o1)[1] = s11;
    }
  }
  __syncthreads();   // the only barrier

  const f32x4 zero = {0.f, 0.f, 0.f, 0.f};
  unsigned pk0[4] = {0xFFFFFFFFu, 0xFFFFFFFFu, 0xFFFFFFFFu, 0xFFFFFFFFu};
  unsigned pk1[4] = {0xFFFFFFFFu, 0xFFFFFFFFu, 0xFFFFFFFFu, 0xFFFFFFFFu};

#pragma unroll 8
  for (int f = 0; f < 32; ++f) {
    // B-frag: lane holds B[k=quad*8+j][col] of centroid half*512 + f*16+col.
    short8 b = sB8[f * 64 + col * 4 + quad];
    float cn = sCn[f * 16 + col];
    f32x4 d0 = __builtin_amdgcn_mfma_f32_16x16x32_bf16(a0, b, zero, 0, 0, 0);
    f32x4 d1 = __builtin_amdgcn_mfma_f32_16x16x32_bf16(a1, b, zero, 0, 0, 0);
    const unsigned idxv = (unsigned)(half * 512 + f * 16 + col);
#pragma unroll
    for (int r = 0; r < 4; ++r) {
      float s0 = d0[r] + cn;
      unsigned q0 = (__builtin_bit_cast(unsigned, s0) & 0xFFFFFC00u) | idxv;
      pk0[r] = pk0[r] < q0 ? pk0[r] : q0;
      float s1 = d1[r] + cn;
      unsigned q1 = (__builtin_bit_cast(unsigned, s1) & 0xFFFFFC00u) | idxv;
      pk1[r] = pk1[r] < q1 ? pk1[r] : q1;
    }
  }

  // Min across the 16 cols of each quad-group (r7-verified).
#pragma unroll
  for (int off = 1; off < 16; off <<= 1) {
#pragma unroll
    for (int r = 0; r < 4; ++r) {
      unsigned o0 = __shfl_xor(pk0[r], off);
      pk0[r] = pk0[r] < o0 ? pk0[r] : o0;
      unsigned o1 = __shfl_xor(pk1[r], off);
      pk1[r] = pk1[r] < o1 ? pk1[r] : o1;
    }
  }

  // Winner write-out using the r3-verified slicing: lanes with q==0 own
  // row t*16 + quad*4 + rsel for t=0,1 -> 32 rows covered exactly once.
  const int rsel = lane & 3;
  const int q = (lane >> 2) & 3;
  if (q == 0) {
#pragma unroll
    for (int t = 0; t < 2; ++t) {
      unsigned pk = (t == 0) ? pk0[rsel] : pk1[rsel];
      int row = rowbase + t * 16 + quad * 4 + rsel;
      wswin[half * N_ROWS + row] = pk;
    }
  }
}

// ---- combine: min over halves + exact fp32 recompute + reduce (r1 shape) --
__global__ __launch_bounds__(256) void combine_kernel(
    const float* __restrict__ lat, const float* __restrict__ cent,
    const unsigned* __restrict__ wswin, float* __restrict__ loss_out) {
  const int row = blockIdx.x * 256 + threadIdx.x;
  unsigned u0 = wswin[row];
  unsigned u1 = wswin[N_ROWS + row];
  unsigned u = u0 < u1 ? u0 : u1;
  int ci = (int)(u & 1023u);

  const float4* zp = (const float4*)(lat + (size_t)row * D);
  const float4* cp = (const float4*)(cent + (size_t)ci * D);
  float m0 = 0.f, m1 = 0.f, m2 = 0.f, m3 = 0.f;
#pragma unroll
  for (int i = 0; i < 8; ++i) {
    float4 z4 = zp[i], c4 = cp[i];
    float f0 = z4.x - c4.x, f1 = z4.y - c4.y;
    float f2 = z4.z - c4.z, f3 = z4.w - c4.w;
    m0 = fmaf(f0, f0, m0); m1 = fmaf(f1, f1, m1);
    m2 = fmaf(f2, f2, m2); m3 = fmaf(f3, f3, m3);
  }
  float dmin = (m0 + m1) + (m2 + m3);

#pragma unroll
  for (int off = 32; off > 0; off >>= 1) dmin += __shfl_down(dmin, off);

  __shared__ float wsum[4];
  const int lane = threadIdx.x & 63;
  const int wave = threadIdx.x >> 6;
  if (lane == 0) wsum[wave] = dmin;
  __syncthreads();
  if (threadIdx.x == 0) {
    float s = (wsum[0] + wsum[1]) + (wsum[2] + wsum[3]);
    atomicAdd(loss_out, s * LOSS_SCALE);
  }
}

extern "C" void kernel_launch(void* const* d_in, const int* in_sizes, int n_in,
                              void* d_out, int out_size, void* d_ws, size_t ws_size,
                              hipStream_t stream) {
  const float* lat  = (const float*)d_in[0];
  const float* cent = (const float*)d_in[1];
  const float* lf   = (const float*)d_in[2];
  float* out = (float*)d_out;
  unsigned short* centbf = (unsigned short*)d_ws;                      // 64 KB
  float* cnormb = (float*)((char*)d_ws + 65536);                       // 4 KB
  unsigned* wswin = (unsigned*)((char*)d_ws + 65536 + 4096);           // 1 MB
  float* loss = out + TOTAL_ELEMS;

  prep_kernel<<<K * D / 256, 256, 0, stream>>>(cent, centbf, cnormb, loss);
  vq_main<<<2048, 256, 0, stream>>>(lat, centbf, cnormb, lf, out, wswin);
  combine_kernel<<<N_ROWS / 256, 256, 0, stream>>>(lat, cent, wswin, loss);
}

// Round 12
// 96.603 us; speedup vs baseline: 1.1076x; 1.1076x over previous
//
#include <hip/hip_runtime.h>

// lat [2048,2048] fp32 -> 131072 rows x D=32; centroids [1024,32] fp32.
// out = [lat * clamp(lf,1e-3,1e3)] ++ [1.25 * mean_{N,D}(min_k ||z-c_k||^2)]
#define D 32
#define K 1024
#define N_ROWS 131072
#define TOTAL_ELEMS 4194304
#define LOSS_SCALE (1.25f / 4194304.0f)
#define BIAS 192.0f   // score = ||c||^2 - 2 z.c + BIAS > 0 -> uint-comparable

typedef __attribute__((ext_vector_type(8))) short short8;   // 8 bf16
typedef __attribute__((ext_vector_type(4))) float f32x4;

__device__ __forceinline__ unsigned short f2bf(float f) {
  unsigned u = __builtin_bit_cast(unsigned, f);
  unsigned r = u + 0x7FFFu + ((u >> 16) & 1u);   // RNE
  return (unsigned short)(r >> 16);
}

// ---- prep: centbf = bf16(-2c); cnormb = ||c||^2 + BIAS; zero loss slot ----
__global__ __launch_bounds__(256) void prep_kernel(
    const float* __restrict__ cent, unsigned short* __restrict__ centbf,
    float* __restrict__ cnormb, float* __restrict__ loss_out) {
  int t = blockIdx.x * 256 + threadIdx.x;   // 0..32767
  centbf[t] = f2bf(-2.0f * cent[t]);
  if (t == 0) *loss_out = 0.0f;
  if (t < K) {
    const float* c = cent + t * D;
    float s0 = 0.f, s1 = 0.f, s2 = 0.f, s3 = 0.f;
#pragma unroll
    for (int d = 0; d < D; d += 4) {
      s0 = fmaf(c[d], c[d], s0);
      s1 = fmaf(c[d + 1], c[d + 1], s1);
      s2 = fmaf(c[d + 2], c[d + 2], s2);
      s3 = fmaf(c[d + 3], c[d + 3], s3);
    }
    cnormb[t] = (s0 + s1) + (s2 + s3) + BIAS;
  }
}

// ---- vq: 8-wave blocks, full-codebook LDS, explicit MFMA/pack pipeline ----
// Grid 512 x 512 threads. Block stages the full 64KB codebook + 4KB cn once;
// each of 8 waves runs the r7/r10-VERIFIED 2-tile 64-iter body barrier-free.
// 2 blocks/CU x 8 waves = 16 waves/CU (4/SIMD). The f-loop is software-
// pipelined: MFMA(f+1) issues before pack(f), hiding MFMA-result latency.
// Arithmetic is bit-identical to r10 (scheduling-only change).
__global__ __launch_bounds__(512) void vq_kernel(
    const float* __restrict__ lat, const float* __restrict__ cent,
    const unsigned short* __restrict__ centbf, const float* __restrict__ cnormb,
    const float* __restrict__ lf_ptr, float* __restrict__ out,
    float* __restrict__ loss_out) {
  __shared__ short8 sB8[4096];   // 64 KB: 1024 centroids x 32 bf16
  __shared__ float sCn[1024];    // 4 KB
  __shared__ float wsum[8];
  const int tid = threadIdx.x;
  const int lane = tid & 63;
  const int wave = tid >> 6;     // 0..7
  const int quad = lane >> 4;
  const int col  = lane & 15;
  const int rowbase = blockIdx.x * 256 + wave * 32;

  // One-time stage of the whole codebook + cnorm (coalesced, 512 threads).
  {
    const short8* gB8 = (const short8*)centbf;   // 4096 chunks
#pragma unroll
    for (int j = 0; j < 8; ++j) sB8[j * 512 + tid] = gB8[j * 512 + tid];
    sCn[tid] = cnormb[tid];
    sCn[512 + tid] = cnormb[512 + tid];
  }

  // A-frags (r7-verified) + fused scale-store.
  float lf = fminf(fmaxf(lf_ptr[0], 0.001f), 1000.0f);
  short8 a0, a1;
  {
    const float* p0 = lat + (size_t)(rowbase + col) * D + quad * 8;
    const float* p1 = p0 + 16 * D;
    float4 u0 = ((const float4*)p0)[0], u1 = ((const float4*)p0)[1];
    float4 w0 = ((const float4*)p1)[0], w1 = ((const float4*)p1)[1];
    a0[0] = (short)f2bf(u0.x); a0[1] = (short)f2bf(u0.y);
    a0[2] = (short)f2bf(u0.z); a0[3] = (short)f2bf(u0.w);
    a0[4] = (short)f2bf(u1.x); a0[5] = (short)f2bf(u1.y);
    a0[6] = (short)f2bf(u1.z); a0[7] = (short)f2bf(u1.w);
    a1[0] = (short)f2bf(w0.x); a1[1] = (short)f2bf(w0.y);
    a1[2] = (short)f2bf(w0.z); a1[3] = (short)f2bf(w0.w);
    a1[4] = (short)f2bf(w1.x); a1[5] = (short)f2bf(w1.y);
    a1[6] = (short)f2bf(w1.z); a1[7] = (short)f2bf(w1.w);
    float* o0 = out + (size_t)(rowbase + col) * D + quad * 8;
    float* o1 = o0 + 16 * D;
    float4 s00 = {u0.x * lf, u0.y * lf, u0.z * lf, u0.w * lf};
    float4 s01 = {u1.x * lf, u1.y * lf, u1.z * lf, u1.w * lf};
    float4 s10 = {w0.x * lf, w0.y * lf, w0.z * lf, w0.w * lf};
    float4 s11 = {w1.x * lf, w1.y * lf, w1.z * lf, w1.w * lf};
    ((float4*)o0)[0] = s00;
    ((float4*)o0)[1] = s01;
    ((float4*)o1)[0] = s10;
    ((float4*)o1)[1] = s11;
  }
  __syncthreads();   // the only barrier before the reduction

  const f32x4 zero = {0.f, 0.f, 0.f, 0.f};
  unsigned pk0[4] = {0xFFFFFFFFu, 0xFFFFFFFFu, 0xFFFFFFFFu, 0xFFFFFFFFu};
  unsigned pk1[4] = {0xFFFFFFFFu, 0xFFFFFFFFu, 0xFFFFFFFFu, 0xFFFFFFFFu};

  const int boff = col * 4 + quad;   // short8-element offset within a 16-cent frag

  // Software pipeline: MFMA(f) in flight while pack(f-1) runs.
  short8 b = sB8[boff];
  float cn = sCn[col];
  f32x4 d0 = __builtin_amdgcn_mfma_f32_16x16x32_bf16(a0, b, zero, 0, 0, 0);
  f32x4 d1 = __builtin_amdgcn_mfma_f32_16x16x32_bf16(a1, b, zero, 0, 0, 0);

#pragma unroll 7
  for (int f = 1; f < 64; ++f) {
    short8 bn = sB8[f * 64 + boff];
    float cnn = sCn[f * 16 + col];
    f32x4 e0 = __builtin_amdgcn_mfma_f32_16x16x32_bf16(a0, bn, zero, 0, 0, 0);
    f32x4 e1 = __builtin_amdgcn_mfma_f32_16x16x32_bf16(a1, bn, zero, 0, 0, 0);
    const unsigned idxv = (unsigned)(((f - 1) << 4) | col);
#pragma unroll
    for (int r = 0; r < 4; ++r) {
      float s0 = d0[r] + cn;
      unsigned q0 = (__builtin_bit_cast(unsigned, s0) & 0xFFFFFC00u) | idxv;
      pk0[r] = min(pk0[r], q0);
      float s1 = d1[r] + cn;
      unsigned q1 = (__builtin_bit_cast(unsigned, s1) & 0xFFFFFC00u) | idxv;
      pk1[r] = min(pk1[r], q1);
    }
    d0 = e0; d1 = e1; cn = cnn;
  }
  {
    const unsigned idxv = (unsigned)((63 << 4) | col);
#pragma unroll
    for (int r = 0; r < 4; ++r) {
      float s0 = d0[r] + cn;
      unsigned q0 = (__builtin_bit_cast(unsigned, s0) & 0xFFFFFC00u) | idxv;
      pk0[r] = min(pk0[r], q0);
      float s1 = d1[r] + cn;
      unsigned q1 = (__builtin_bit_cast(unsigned, s1) & 0xFFFFFC00u) | idxv;
      pk1[r] = min(pk1[r], q1);
    }
  }

  // Min across the 16 cols of each quad-group (r7-verified).
#pragma unroll
  for (int off = 1; off < 16; off <<= 1) {
#pragma unroll
    for (int r = 0; r < 4; ++r) {
      unsigned o0 = __shfl_xor(pk0[r], off);
      pk0[r] = min(pk0[r], o0);
      unsigned o1 = __shfl_xor(pk1[r], off);
      pk1[r] = min(pk1[r], o1);
    }
  }

  // Exact fp32 recompute of d_min for winners (r3/r7-verified slicing).
  const int rsel = lane & 3;
  const int q = (lane >> 2) & 3;
  float s = 0.f;
#pragma unroll
  for (int t = 0; t < 2; ++t) {
    unsigned pk = (t == 0) ? pk0[rsel] : pk1[rsel];
    int row = rowbase + t * 16 + quad * 4 + rsel;
    int ci = (int)(pk & 1023u);
    const float* zp = lat + (size_t)row * D + q * 8;
    const float* cp = cent + (size_t)ci * D + q * 8;
    float4 za = ((const float4*)zp)[0], zb = ((const float4*)zp)[1];
    float4 ca = ((const float4*)cp)[0], cb = ((const float4*)cp)[1];
    float f0 = za.x - ca.x, f1 = za.y - ca.y, f2 = za.z - ca.z, f3 = za.w - ca.w;
    float g0 = zb.x - cb.x, g1 = zb.y - cb.y, g2 = zb.z - cb.z, g3 = zb.w - cb.w;
    float m0 = fmaf(f0, f0, g0 * g0);
    float m1 = fmaf(f1, f1, g1 * g1);
    float m2 = fmaf(f2, f2, g2 * g2);
    float m3 = fmaf(f3, f3, g3 * g3);
    s += (m0 + m1) + (m2 + m3);
  }
  // Full 64-lane butterfly: all-lane sum counts each of the 32 rows once.
  s += __shfl_xor(s, 4);
  s += __shfl_xor(s, 8);
  s += __shfl_xor(s, 1);
  s += __shfl_xor(s, 2);
  s += __shfl_xor(s, 16);
  s += __shfl_xor(s, 32);

  if (lane == 0) wsum[wave] = s;
  __syncthreads();
  if (tid == 0) {
    float blk = ((wsum[0] + wsum[1]) + (wsum[2] + wsum[3])) +
                ((wsum[4] + wsum[5]) + (wsum[6] + wsum[7]));
    atomicAdd(loss_out, blk * LOSS_SCALE);
  }
}

extern "C" void kernel_launch(void* const* d_in, const int* in_sizes, int n_in,
                              void* d_out, int out_size, void* d_ws, size_t ws_size,
                              hipStream_t stream) {
  const float* lat  = (const float*)d_in[0];
  const float* cent = (const float*)d_in[1];
  const float* lf   = (const float*)d_in[2];
  float* out = (float*)d_out;
  unsigned short* centbf = (unsigned short*)d_ws;                 // 64 KB
  float* cnormb = (float*)((char*)d_ws + K * D * sizeof(unsigned short));
  float* loss = out + TOTAL_ELEMS;

  prep_kernel<<<K * D / 256, 256, 0, stream>>>(cent, centbf, cnormb, loss);
  vq_kernel<<<N_ROWS / 256, 512, 0, stream>>>(lat, cent, centbf, cnormb, lf,
                                              out, loss);
}

// Round 13
// 87.778 us; speedup vs baseline: 1.2189x; 1.1005x over previous
//
#include <hip/hip_runtime.h>

// lat [2048,2048] fp32 -> 131072 rows x D=32; centroids [1024,32] fp32.
// out = [lat * clamp(lf,1e-3,1e3)] ++ [1.25 * mean_{N,D}(min_k ||z-c_k||^2)]
#define D 32
#define K 1024
#define N_ROWS 131072
#define TOTAL_ELEMS 4194304
#define LOSS_SCALE (1.25f / 4194304.0f)

typedef __attribute__((ext_vector_type(8))) short short8;   // 8 bf16
typedef __attribute__((ext_vector_type(4))) float f32x4;

__device__ __forceinline__ unsigned short f2bf(float f) {
  unsigned u = __builtin_bit_cast(unsigned, f);
  unsigned r = u + 0x7FFFu + ((u >> 16) & 1u);   // RNE
  return (unsigned short)(r >> 16);
}

// ---- prep: centbf = bf16(-2c); cnormb = ||c||^2 (no bias); loss = 0 -------
__global__ __launch_bounds__(256) void prep_kernel(
    const float* __restrict__ cent, unsigned short* __restrict__ centbf,
    float* __restrict__ cnormb, float* __restrict__ loss_out) {
  int t = blockIdx.x * 256 + threadIdx.x;   // 0..32767
  centbf[t] = f2bf(-2.0f * cent[t]);
  if (t == 0) *loss_out = 0.0f;
  if (t < K) {
    const float* c = cent + t * D;
    float s0 = 0.f, s1 = 0.f, s2 = 0.f, s3 = 0.f;
#pragma unroll
    for (int d = 0; d < D; d += 4) {
      s0 = fmaf(c[d], c[d], s0);
      s1 = fmaf(c[d + 1], c[d + 1], s1);
      s2 = fmaf(c[d + 2], c[d + 2], s2);
      s3 = fmaf(c[d + 3], c[d + 3], s3);
    }
    cnormb[t] = (s0 + s1) + (s2 + s3);
  }
}

// ---- vq: index-free fp32-min MFMA search + fused scale-store --------------
// r12 structure (512 thr, 8 waves, full 64KB codebook in LDS, barrier-free)
// with the pack reduced to add+v_min_f32 (2 VALU/score, no idx/mask/BIAS)
// and the winner-recompute epilogue replaced by min-value + fp32 ||z||^2.
// loss = sum_rows( min_k(-2z.c_bf16 + ||c||^2) + ||z||^2 ) * LOSS_SCALE.
__global__ __launch_bounds__(512) void vq_kernel(
    const float* __restrict__ lat, const unsigned short* __restrict__ centbf,
    const float* __restrict__ cnormb, const float* __restrict__ lf_ptr,
    float* __restrict__ out, float* __restrict__ loss_out) {
  __shared__ short8 sB8[4096];   // 64 KB: 1024 centroids x 32 bf16
  __shared__ float sCn[1024];    // 4 KB
  __shared__ float wsum[8];
  const int tid = threadIdx.x;
  const int lane = tid & 63;
  const int wave = tid >> 6;     // 0..7
  const int quad = lane >> 4;
  const int col  = lane & 15;
  const int rowbase = blockIdx.x * 256 + wave * 32;

  // One-time stage of the whole codebook + cnorm (coalesced, 512 threads).
  {
    const short8* gB8 = (const short8*)centbf;   // 4096 chunks
#pragma unroll
    for (int j = 0; j < 8; ++j) sB8[j * 512 + tid] = gB8[j * 512 + tid];
    sCn[tid] = cnormb[tid];
    sCn[512 + tid] = cnormb[512 + tid];
  }

  // A-frags (r7-verified layout) + fused scale-store + fp32 ||z||^2 partial.
  float lf = fminf(fmaxf(lf_ptr[0], 0.001f), 1000.0f);
  short8 a0, a1;
  float zz;
  {
    const float* p0 = lat + (size_t)(rowbase + col) * D + quad * 8;
    const float* p1 = p0 + 16 * D;
    float4 u0 = ((const float4*)p0)[0], u1 = ((const float4*)p0)[1];
    float4 w0 = ((const float4*)p1)[0], w1 = ((const float4*)p1)[1];
    a0[0] = (short)f2bf(u0.x); a0[1] = (short)f2bf(u0.y);
    a0[2] = (short)f2bf(u0.z); a0[3] = (short)f2bf(u0.w);
    a0[4] = (short)f2bf(u1.x); a0[5] = (short)f2bf(u1.y);
    a0[6] = (short)f2bf(u1.z); a0[7] = (short)f2bf(u1.w);
    a1[0] = (short)f2bf(w0.x); a1[1] = (short)f2bf(w0.y);
    a1[2] = (short)f2bf(w0.z); a1[3] = (short)f2bf(w0.w);
    a1[4] = (short)f2bf(w1.x); a1[5] = (short)f2bf(w1.y);
    a1[6] = (short)f2bf(w1.z); a1[7] = (short)f2bf(w1.w);
    // ||z||^2 partial: these 16 floats, each tile element counted once
    // across the wave (same coverage proof as the scale-store).
    float t0 = fmaf(u0.x, u0.x, fmaf(u0.y, u0.y, fmaf(u0.z, u0.z, u0.w * u0.w)));
    float t1 = fmaf(u1.x, u1.x, fmaf(u1.y, u1.y, fmaf(u1.z, u1.z, u1.w * u1.w)));
    float t2 = fmaf(w0.x, w0.x, fmaf(w0.y, w0.y, fmaf(w0.z, w0.z, w0.w * w0.w)));
    float t3 = fmaf(w1.x, w1.x, fmaf(w1.y, w1.y, fmaf(w1.z, w1.z, w1.w * w1.w)));
    zz = (t0 + t1) + (t2 + t3);
    float* o0 = out + (size_t)(rowbase + col) * D + quad * 8;
    float* o1 = o0 + 16 * D;
    float4 s00 = {u0.x * lf, u0.y * lf, u0.z * lf, u0.w * lf};
    float4 s01 = {u1.x * lf, u1.y * lf, u1.z * lf, u1.w * lf};
    float4 s10 = {w0.x * lf, w0.y * lf, w0.z * lf, w0.w * lf};
    float4 s11 = {w1.x * lf, w1.y * lf, w1.z * lf, w1.w * lf};
    ((float4*)o0)[0] = s00;
    ((float4*)o0)[1] = s01;
    ((float4*)o1)[0] = s10;
    ((float4*)o1)[1] = s11;
  }
  __syncthreads();   // the only barrier before the reduction

  const f32x4 zero = {0.f, 0.f, 0.f, 0.f};
  const float INF = 3.4e38f;
  float m0[4] = {INF, INF, INF, INF};
  float m1[4] = {INF, INF, INF, INF};
  const int boff = col * 4 + quad;   // short8 offset within a 16-cent frag

#pragma unroll 8
  for (int f = 0; f < 64; ++f) {
    // B-frag: lane holds B[k=quad*8+j][col] of centroid f*16+col (r3-verified).
    short8 b = sB8[f * 64 + boff];
    float cn = sCn[f * 16 + col];
    f32x4 d0 = __builtin_amdgcn_mfma_f32_16x16x32_bf16(a0, b, zero, 0, 0, 0);
    f32x4 d1 = __builtin_amdgcn_mfma_f32_16x16x32_bf16(a1, b, zero, 0, 0, 0);
#pragma unroll
    for (int r = 0; r < 4; ++r) {
      m0[r] = fminf(m0[r], d0[r] + cn);   // add + v_min_f32: 2 VALU/score
      m1[r] = fminf(m1[r], d1[r] + cn);
    }
  }

  // Min across the 16 cols of each quad-group (lane bits 0..3).
#pragma unroll
  for (int off = 1; off < 16; off <<= 1) {
#pragma unroll
    for (int r = 0; r < 4; ++r) {
      m0[r] = fminf(m0[r], __shfl_xor(m0[r], off));
      m1[r] = fminf(m1[r], __shfl_xor(m1[r], off));
    }
  }

  // m0[r] = row-min for row quad*4+r (tile0); m1[r] for row 16+quad*4+r
  // (tile1), uniform within each 16-lane quad group (C/D layout, verified).
  // Sum this quad's 8 rows, then combine the 4 quads via lane bits 4,5.
  float s = ((m0[0] + m0[1]) + (m0[2] + m0[3])) +
            ((m1[0] + m1[1]) + (m1[2] + m1[3]));
  s += __shfl_xor(s, 16);
  s += __shfl_xor(s, 32);   // now = sum of all 32 row-mins of this wave

  // Wave sum of ||z||^2 partials (every tile element exactly once).
  zz += __shfl_xor(zz, 1);
  zz += __shfl_xor(zz, 2);
  zz += __shfl_xor(zz, 4);
  zz += __shfl_xor(zz, 8);
  zz += __shfl_xor(zz, 16);
  zz += __shfl_xor(zz, 32);

  if (lane == 0) wsum[wave] = s + zz;   // sum_rows dmin for this wave
  __syncthreads();
  if (tid == 0) {
    float blk = ((wsum[0] + wsum[1]) + (wsum[2] + wsum[3])) +
                ((wsum[4] + wsum[5]) + (wsum[6] + wsum[7]));
    atomicAdd(loss_out, blk * LOSS_SCALE);
  }
}

extern "C" void kernel_launch(void* const* d_in, const int* in_sizes, int n_in,
                              void* d_out, int out_size, void* d_ws, size_t ws_size,
                              hipStream_t stream) {
  const float* lat  = (const float*)d_in[0];
  const float* cent = (const float*)d_in[1];
  const float* lf   = (const float*)d_in[2];
  float* out = (float*)d_out;
  unsigned short* centbf = (unsigned short*)d_ws;                 // 64 KB
  float* cnormb = (float*)((char*)d_ws + K * D * sizeof(unsigned short));
  float* loss = out + TOTAL_ELEMS;

  prep_kernel<<<K * D / 256, 256, 0, stream>>>(cent, centbf, cnormb, loss);
  vq_kernel<<<N_ROWS / 256, 512, 0, stream>>>(lat, centbf, cnormb, lf,
                                              out, loss);
}

// Round 14
// 87.383 us; speedup vs baseline: 1.2244x; 1.0045x over previous
//
#include <hip/hip_runtime.h>

// lat [2048,2048] fp32 -> 131072 rows x D=32; centroids [1024,32] fp32.
// out = [lat * clamp(lf,1e-3,1e3)] ++ [1.25 * mean_{N,D}(min_k ||z-c_k||^2)]
#define D 32
#define K 1024
#define N_ROWS 131072
#define TOTAL_ELEMS 4194304
#define LOSS_SCALE (1.25f / 4194304.0f)

typedef __attribute__((ext_vector_type(8))) short short8;   // 8 bf16
typedef __attribute__((ext_vector_type(4))) float f32x4;

__device__ __forceinline__ unsigned short f2bf(float f) {
  unsigned u = __builtin_bit_cast(unsigned, f);
  unsigned r = u + 0x7FFFu + ((u >> 16) & 1u);   // RNE
  return (unsigned short)(r >> 16);
}

// ---- prep: centbf = bf16(-2c); cnormb4 = {cn,cn,cn,cn}; loss = 0 ----------
__global__ __launch_bounds__(256) void prep_kernel(
    const float* __restrict__ cent, unsigned short* __restrict__ centbf,
    float4* __restrict__ cnormb4, float* __restrict__ loss_out) {
  int t = blockIdx.x * 256 + threadIdx.x;   // 0..32767
  centbf[t] = f2bf(-2.0f * cent[t]);
  if (t == 0) *loss_out = 0.0f;
  if (t < K) {
    const float* c = cent + t * D;
    float s0 = 0.f, s1 = 0.f, s2 = 0.f, s3 = 0.f;
#pragma unroll
    for (int d = 0; d < D; d += 4) {
      s0 = fmaf(c[d], c[d], s0);
      s1 = fmaf(c[d + 1], c[d + 1], s1);
      s2 = fmaf(c[d + 2], c[d + 2], s2);
      s3 = fmaf(c[d + 3], c[d + 3], s3);
    }
    float cn = (s0 + s1) + (s2 + s3);
    cnormb4[t] = make_float4(cn, cn, cn, cn);   // pre-broadcast for MFMA C
  }
}

// ---- vq: cn-in-MFMA-C, index-free fp32-min search + fused scale-store -----
// r13 PASSING structure (512 thr, 8 waves, 2-tile body, barrier-free loop)
// with the per-centroid bias folded into the MFMA C operand, loaded as a
// pre-replicated f32x4 from LDS. Pack = 8 v_min_f32/iter (was 8 add + 8 min).
// This is also the bisect on the r4 bug: 2-tile + cn-in-C only.
__global__ __launch_bounds__(512) void vq_kernel(
    const float* __restrict__ lat, const unsigned short* __restrict__ centbf,
    const float4* __restrict__ cnormb4, const float* __restrict__ lf_ptr,
    float* __restrict__ out, float* __restrict__ loss_out) {
  __shared__ short8 sB8[4096];   // 64 KB: 1024 centroids x 32 bf16
  __shared__ f32x4 sCn4[1024];   // 16 KB: {cn,cn,cn,cn} per centroid
  // total 80 KB -> exactly 2 blocks/CU; wsum reuses sB8 after the f-loop.
  const int tid = threadIdx.x;
  const int lane = tid & 63;
  const int wave = tid >> 6;     // 0..7
  const int quad = lane >> 4;
  const int col  = lane & 15;
  const int rowbase = blockIdx.x * 256 + wave * 32;

  // One-time stage of codebook + replicated cnorm (coalesced, 512 threads).
  {
    const short8* gB8 = (const short8*)centbf;   // 4096 chunks
#pragma unroll
    for (int j = 0; j < 8; ++j) sB8[j * 512 + tid] = gB8[j * 512 + tid];
    const uint4* g4 = (const uint4*)cnormb4;     // 1024 chunks
    uint4* s4 = (uint4*)sCn4;
    s4[tid] = g4[tid];
    s4[512 + tid] = g4[512 + tid];
  }

  // A-frags (r7-verified layout) + fused scale-store + fp32 ||z||^2 partial.
  float lf = fminf(fmaxf(lf_ptr[0], 0.001f), 1000.0f);
  short8 a0, a1;
  float zz;
  {
    const float* p0 = lat + (size_t)(rowbase + col) * D + quad * 8;
    const float* p1 = p0 + 16 * D;
    float4 u0 = ((const float4*)p0)[0], u1 = ((const float4*)p0)[1];
    float4 w0 = ((const float4*)p1)[0], w1 = ((const float4*)p1)[1];
    a0[0] = (short)f2bf(u0.x); a0[1] = (short)f2bf(u0.y);
    a0[2] = (short)f2bf(u0.z); a0[3] = (short)f2bf(u0.w);
    a0[4] = (short)f2bf(u1.x); a0[5] = (short)f2bf(u1.y);
    a0[6] = (short)f2bf(u1.z); a0[7] = (short)f2bf(u1.w);
    a1[0] = (short)f2bf(w0.x); a1[1] = (short)f2bf(w0.y);
    a1[2] = (short)f2bf(w0.z); a1[3] = (short)f2bf(w0.w);
    a1[4] = (short)f2bf(w1.x); a1[5] = (short)f2bf(w1.y);
    a1[6] = (short)f2bf(w1.z); a1[7] = (short)f2bf(w1.w);
    float t0 = fmaf(u0.x, u0.x, fmaf(u0.y, u0.y, fmaf(u0.z, u0.z, u0.w * u0.w)));
    float t1 = fmaf(u1.x, u1.x, fmaf(u1.y, u1.y, fmaf(u1.z, u1.z, u1.w * u1.w)));
    float t2 = fmaf(w0.x, w0.x, fmaf(w0.y, w0.y, fmaf(w0.z, w0.z, w0.w * w0.w)));
    float t3 = fmaf(w1.x, w1.x, fmaf(w1.y, w1.y, fmaf(w1.z, w1.z, w1.w * w1.w)));
    zz = (t0 + t1) + (t2 + t3);
    float* o0 = out + (size_t)(rowbase + col) * D + quad * 8;
    float* o1 = o0 + 16 * D;
    float4 s00 = {u0.x * lf, u0.y * lf, u0.z * lf, u0.w * lf};
    float4 s01 = {u1.x * lf, u1.y * lf, u1.z * lf, u1.w * lf};
    float4 s10 = {w0.x * lf, w0.y * lf, w0.z * lf, w0.w * lf};
    float4 s11 = {w1.x * lf, w1.y * lf, w1.z * lf, w1.w * lf};
    ((float4*)o0)[0] = s00;
    ((float4*)o0)[1] = s01;
    ((float4*)o1)[0] = s10;
    ((float4*)o1)[1] = s11;
  }
  __syncthreads();

  const float INF = 3.4e38f;
  float m0[4] = {INF, INF, INF, INF};
  float m1[4] = {INF, INF, INF, INF};
  const int boff = col * 4 + quad;   // short8 offset within a 16-cent frag

#pragma unroll 8
  for (int f = 0; f < 64; ++f) {
    // B-frag (r3-verified) + pre-replicated C = {cn,cn,cn,cn} for this col.
    short8 b = sB8[f * 64 + boff];
    f32x4 c4 = sCn4[f * 16 + col];
    f32x4 d0 = __builtin_amdgcn_mfma_f32_16x16x32_bf16(a0, b, c4, 0, 0, 0);
    f32x4 d1 = __builtin_amdgcn_mfma_f32_16x16x32_bf16(a1, b, c4, 0, 0, 0);
#pragma unroll
    for (int r = 0; r < 4; ++r) {
      m0[r] = fminf(m0[r], d0[r]);   // score = dot + cn came out of the MFMA
      m1[r] = fminf(m1[r], d1[r]);
    }
  }

  // Min across the 16 cols of each quad-group (lane bits 0..3).
#pragma unroll
  for (int off = 1; off < 16; off <<= 1) {
#pragma unroll
    for (int r = 0; r < 4; ++r) {
      m0[r] = fminf(m0[r], __shfl_xor(m0[r], off));
      m1[r] = fminf(m1[r], __shfl_xor(m1[r], off));
    }
  }

  // Row-min sums (r13-verified): quad's 8 rows, then quads via bits 4,5.
  float s = ((m0[0] + m0[1]) + (m0[2] + m0[3])) +
            ((m1[0] + m1[1]) + (m1[2] + m1[3]));
  s += __shfl_xor(s, 16);
  s += __shfl_xor(s, 32);

  // Wave sum of ||z||^2 partials (every element exactly once).
  zz += __shfl_xor(zz, 1);
  zz += __shfl_xor(zz, 2);
  zz += __shfl_xor(zz, 4);
  zz += __shfl_xor(zz, 8);
  zz += __shfl_xor(zz, 16);
  zz += __shfl_xor(zz, 32);

  float total = s + zz;
  __syncthreads();                  // all waves done reading sB8/sCn4
  float* wsum = (float*)sB8;        // reuse dead codebook LDS
  if (lane == 0) wsum[wave] = total;
  __syncthreads();
  if (tid == 0) {
    float blk = ((wsum[0] + wsum[1]) + (wsum[2] + wsum[3])) +
                ((wsum[4] + wsum[5]) + (wsum[6] + wsum[7]));
    atomicAdd(loss_out, blk * LOSS_SCALE);
  }
}

extern "C" void kernel_launch(void* const* d_in, const int* in_sizes, int n_in,
                              void* d_out, int out_size, void* d_ws, size_t ws_size,
                              hipStream_t stream) {
  const float* lat  = (const float*)d_in[0];
  const float* cent = (const float*)d_in[1];
  const float* lf   = (const float*)d_in[2];
  float* out = (float*)d_out;
  unsigned short* centbf = (unsigned short*)d_ws;                 // 64 KB
  float4* cnormb4 = (float4*)((char*)d_ws + 65536);               // 16 KB
  float* loss = out + TOTAL_ELEMS;

  prep_kernel<<<K * D / 256, 256, 0, stream>>>(cent, centbf, cnormb4, loss);
  vq_kernel<<<N_ROWS / 256, 512, 0, stream>>>(lat, centbf, cnormb4, lf,
                                              out, loss);
}